// Round 5
// baseline (316.447 us; speedup 1.0000x reference)
//
#include <hip/hip_runtime.h>
#include <math.h>

// Problem constants
#define BB   8
#define HW   4096
#define BHW  32768
#define DIM  256
#define CR   64
#define GC   32
#define NHD  4
#define HC   16
#define NTAP 9
#define NCLS 80

// workspace layout (float offsets)
#define OFF_QP   0u          // q planar   [B][64][H][W]            2,097,152
#define OFF_QT   2097152u    // q pix-major[B*HW][64]               2,097,152
#define OFF_KT   4194304u    // KV interleaved [BG][HW][2][32]      4,194,304  (k16|v16 per sub)
#define OFF_T    8388608u    // t planar   [BG][32][H][W]           2,097,152
// --- overlap region: inside OFF_T's span, used only BEFORE k2 writes T ---
#define OFF_WQT  8388608u    // wqkv^T * g1  [256][192]             49,152
#define OFF_AB   8437760u    // A[192], B[192]                      384
#define OFF_STAT 8438144u    // m[32768], rs[32768]                 65,536
// ------------------------------------------------------------------------
#define OFF_OFFB 10485760u   // off planar [BG][18][H][W]           1,179,648
#define OFF_AOT  11665408u   // attn out   [64][B*HW] planar        2,097,152
#define OFF_WPT  13762560u   // wproj^T [64][256]                   16,384
#define OFF_WCT  13778944u   // wcls^T  [256][80]                   20,480
#define OFF_WFT  13799424u   // woff^T  [9][32][18]                 5,184

// ---------------- k0a: weight transposes ----------------
__global__ __launch_bounds__(256) void k0a_transpose(
    const float* __restrict__ wqkv, const float* __restrict__ g1,
    const float* __restrict__ wproj, const float* __restrict__ wcls,
    float* __restrict__ ws)
{
    const int c = blockIdx.x;   // 0..255
    const int t = threadIdx.x;
    if (t < 192) ws[OFF_WQT + c * 192 + t] = wqkv[t * 256 + c] * g1[c];
    if (c < 64)  ws[OFF_WPT + c * 256 + t] = wproj[t * 64 + c];
    if (t < 80)  ws[OFF_WCT + c * 80 + t]  = wcls[t * 256 + c];
}

// ---------------- k0b: A/B LN-fold vectors + woff transpose ----------------
__global__ __launch_bounds__(192) void k0b_ab(
    const float* __restrict__ wqkv, const float* __restrict__ g1,
    const float* __restrict__ b1, const float* __restrict__ woff,
    float* __restrict__ ws)
{
    const int t = threadIdx.x; // 0..191
    float a = 0.f, bb = 0.f;
    for (int c = 0; c < 256; ++c) {
        float w = wqkv[t * 256 + c];
        a += w * g1[c]; bb += w * b1[c];
    }
    ws[OFF_AB + t] = a;
    ws[OFF_AB + 192 + t] = bb;
    for (int pair = t; pair < 288; pair += 192) {
        int wo = pair >> 5, ic = pair & 31;
        for (int o = 0; o < 18; ++o)
            ws[OFF_WFT + (wo * 32 + ic) * 18 + o] = woff[(o * 32 + ic) * 9 + wo];
    }
}

// ---------------- k0c: per-pixel LN stats ----------------
__global__ __launch_bounds__(256) void k0c_stats(
    const float* __restrict__ x, float* __restrict__ ws)
{
    __shared__ float psum[256], psq[256];
    const int t = threadIdx.x;
    const int b = blockIdx.x >> 6, row = blockIdx.x & 63;
    const int p = t & 63, q4 = t >> 6;
    const int colbase = row * 64 + p;
    float s = 0.f, ss = 0.f;
    for (int i = 0; i < 64; ++i) {
        int c = q4 * 64 + i;
        float v = x[(size_t)(b * DIM + c) * HW + colbase];
        s += v; ss += v * v;
    }
    psum[t] = s; psq[t] = ss;
    __syncthreads();
    if (t < 64) {
        float S = psum[t] + psum[64 + t] + psum[128 + t] + psum[192 + t];
        float Q = psq[t] + psq[64 + t] + psq[128 + t] + psq[192 + t];
        float m = S * (1.f / 256.f);
        float v = Q * (1.f / 256.f) - m * m;
        float* stat = ws + OFF_STAT;
        int gp = b * HW + row * 64 + t;
        stat[gp] = m;
        stat[BHW + gp] = rsqrtf(v + 1e-5f);
    }
}

// ---------------- k1: QKV GEMM (LN folded; coalesced epilogue) ----------------
// grid 1024: mhalf=blk>>9 (96 outputs each), (b,row)=blk&511. block 256.
__global__ __launch_bounds__(256) void k1_gemm(
    const float* __restrict__ x, float* __restrict__ ws)
{
    __shared__ float smem[8192];     // 2x 16KB staging; reused as 64x97 transpose tile
    const int t = threadIdx.x;
    const int mhalf = blockIdx.x >> 9;
    const int rb = blockIdx.x & 511;
    const int b = rb >> 6, row = rb & 63;
    const int p = t & 63;
    const int og = __builtin_amdgcn_readfirstlane(t >> 6);
    const int obase = mhalf * 96 + og * 24;
    const float* wqT = ws + OFF_WQT;
    const float* AB  = ws + OFF_AB;
    const float* stat = ws + OFF_STAT;
    const size_t xbase = (size_t)b * DIM * HW + row * 64;

    float acc[24];
    #pragma unroll
    for (int j = 0; j < 24; ++j) acc[j] = 0.f;

    #pragma unroll
    for (int j = 0; j < 4; ++j) {
        int idx4 = t + j * 256;
        int c = idx4 >> 4, p4 = (idx4 & 15) << 2;
        float4 v = *(const float4*)&x[xbase + (size_t)c * HW + p4];
        *(float4*)&smem[c * 64 + p4] = v;
    }
    __syncthreads();

    for (int kt = 0; kt < 4; ++kt) {
        const int cur = kt & 1;
        float4 pf[4];
        if (kt < 3) {
            #pragma unroll
            for (int j = 0; j < 4; ++j) {
                int idx4 = t + j * 256;
                int c = idx4 >> 4, p4 = (idx4 & 15) << 2;
                pf[j] = *(const float4*)&x[xbase + (size_t)((kt + 1) * 64 + c) * HW + p4];
            }
        }
        const float* wb = wqT + (size_t)kt * 64 * 192 + obase;
        #pragma unroll 8
        for (int c = 0; c < 64; ++c) {
            float xv = smem[cur * 4096 + c * 64 + p];
            #pragma unroll
            for (int j = 0; j < 24; ++j)
                acc[j] += wb[c * 192 + j] * xv;
        }
        if (kt < 3) {
            #pragma unroll
            for (int j = 0; j < 4; ++j) {
                int idx4 = t + j * 256;
                int c = idx4 >> 4, p4 = (idx4 & 15) << 2;
                *(float4*)&smem[(cur ^ 1) * 4096 + c * 64 + p4] = pf[j];
            }
            __syncthreads();
        }
    }
    __syncthreads();

    const int colbase = row * 64 + p;
    const int gp = b * HW + colbase;
    const float m = stat[gp], rsv = stat[BHW + gp];
    #pragma unroll
    for (int j = 0; j < 24; ++j) {
        int o = obase + j;
        smem[p * 97 + og * 24 + j] = rsv * (acc[j] - m * AB[o]) + AB[192 + o];
    }
    __syncthreads();

    float* qp  = ws + OFF_QP;
    float* qt  = ws + OFF_QT;
    float* kvb = ws + OFF_KT;
    const int colrow = row * 64;
    if (mhalf == 0) {
        // q planar
        #pragma unroll
        for (int it = 0; it < 16; ++it) {
            int idx = it * 256 + t;
            int o = idx >> 6, px = idx & 63;
            qp[(size_t)(b * 64 + o) * HW + colrow + px] = smem[px * 97 + o];
        }
        // q pixel-major
        #pragma unroll
        for (int it = 0; it < 16; ++it) {
            int idx = it * 256 + t;
            int px = idx >> 6, o = idx & 63;
            qt[((size_t)(b * HW + colrow + px)) * 64 + o] = smem[px * 97 + o];
        }
        // k of bg=2b (tile cols 64..95), slot j
        #pragma unroll
        for (int it = 0; it < 8; ++it) {
            int idx = it * 256 + t;
            int px = idx >> 5, sub = (idx >> 4) & 1, j = idx & 15;
            kvb[(((size_t)(2 * b) * HW + colrow + px) * 2 + sub) * 32 + j]
                = smem[px * 97 + 64 + sub * 16 + j];
        }
    } else {
        // k of bg=2b+1 (cols 0..31), slot j
        #pragma unroll
        for (int it = 0; it < 8; ++it) {
            int idx = it * 256 + t;
            int px = idx >> 5, sub = (idx >> 4) & 1, j = idx & 15;
            kvb[(((size_t)(2 * b + 1) * HW + colrow + px) * 2 + sub) * 32 + j]
                = smem[px * 97 + sub * 16 + j];
        }
        // v of bg=2b (cols 32..63), slot 16+j
        #pragma unroll
        for (int it = 0; it < 8; ++it) {
            int idx = it * 256 + t;
            int px = idx >> 5, sub = (idx >> 4) & 1, j = idx & 15;
            kvb[(((size_t)(2 * b) * HW + colrow + px) * 2 + sub) * 32 + 16 + j]
                = smem[px * 97 + 32 + sub * 16 + j];
        }
        // v of bg=2b+1 (cols 64..95), slot 16+j
        #pragma unroll
        for (int it = 0; it < 8; ++it) {
            int idx = it * 256 + t;
            int px = idx >> 5, sub = (idx >> 4) & 1, j = idx & 15;
            kvb[(((size_t)(2 * b + 1) * HW + colrow + px) * 2 + sub) * 32 + 16 + j]
                = smem[px * 97 + 64 + sub * 16 + j];
        }
    }
}

// ------- k2: depthwise 3x3 + LN(32) + GELU, channel-split across waves -------
__global__ __launch_bounds__(256) void k2_off_feat(
    const float* __restrict__ wdw, const float* __restrict__ g2, const float* __restrict__ b2,
    float* __restrict__ ws)
{
    __shared__ float rsum[4][64], rsq[4][64], smv[64], srv[64];
    const int t = threadIdx.x;
    const int bg = blockIdx.x >> 6, row = blockIdx.x & 63;
    const int p = t & 63;
    const int cq = __builtin_amdgcn_readfirstlane(t >> 6);
    const int b = bg >> 1, g = bg & 1;
    const float* qp = ws + OFF_QP;
    float vals[8];
    float s = 0.f, ss = 0.f;
    #pragma unroll
    for (int i = 0; i < 8; ++i) {
        int ch = cq * 8 + i;
        const float* plane = qp + (size_t)(b * 64 + g * 32 + ch) * HW;
        float a = 0.f;
        #pragma unroll
        for (int dy = 0; dy < 3; ++dy) {
            int y = row + dy - 1;
            if ((unsigned)y >= 64u) continue;
            #pragma unroll
            for (int dx = 0; dx < 3; ++dx) {
                int xx = p + dx - 1;
                bool vld = (unsigned)xx < 64u;
                float q = plane[y * 64 + (vld ? xx : 0)];
                a += (vld ? q : 0.f) * wdw[ch * 9 + dy * 3 + dx];
            }
        }
        vals[i] = a; s += a; ss += a * a;
    }
    rsum[cq][p] = s; rsq[cq][p] = ss;
    __syncthreads();
    if (t < 64) {
        float S = rsum[0][t] + rsum[1][t] + rsum[2][t] + rsum[3][t];
        float Q = rsq[0][t] + rsq[1][t] + rsq[2][t] + rsq[3][t];
        float m = S * (1.f / 32.f);
        float v = Q * (1.f / 32.f) - m * m;
        smv[t] = m; srv[t] = rsqrtf(v + 1e-5f);
    }
    __syncthreads();
    float m = smv[p], rv = srv[p];
    float* tb = ws + OFF_T;
    #pragma unroll
    for (int i = 0; i < 8; ++i) {
        int ch = cq * 8 + i;
        float u = (vals[i] - m) * rv * g2[ch] + b2[ch];
        float ge = 0.5f * u * (1.f + erff(u * 0.70710678118654752f));
        tb[(size_t)(bg * 32 + ch) * HW + row * 64 + p] = ge;
    }
}

// ------- k3: 3x3 conv 32->18 + tanh*5 + base offset, ic-split across waves -------
__global__ __launch_bounds__(256) void k3_pred_off(
    const float* __restrict__ boff, const float* __restrict__ off_in,
    float* __restrict__ ws)
{
    __shared__ float part[4 * 18 * 64];
    const int t = threadIdx.x;
    const int bg = blockIdx.x >> 6, row = blockIdx.x & 63;
    const int p = t & 63;
    const int icq = __builtin_amdgcn_readfirstlane(t >> 6);
    const int b = bg >> 1;
    const float* tb = ws + OFF_T;
    const float* wfT = ws + OFF_WFT;
    float acc[18];
    #pragma unroll
    for (int o = 0; o < 18; ++o) acc[o] = 0.f;
    #pragma unroll
    for (int dy = 0; dy < 3; ++dy) {
        int y = row + dy - 1;
        if ((unsigned)y >= 64u) continue;
        #pragma unroll
        for (int dx = 0; dx < 3; ++dx) {
            int xx = p + dx - 1;
            bool vld = (unsigned)xx < 64u;
            int xc = vld ? xx : 0;
            int wo = dy * 3 + dx;
            #pragma unroll
            for (int i = 0; i < 8; ++i) {
                int ic = icq * 8 + i;
                float tv = tb[(size_t)(bg * 32 + ic) * HW + y * 64 + xc];
                tv = vld ? tv : 0.f;
                const float* wrow = wfT + (wo * 32 + ic) * 18;
                #pragma unroll
                for (int o = 0; o < 18; ++o)
                    acc[o] += tv * wrow[o];
            }
        }
    }
    #pragma unroll
    for (int o = 0; o < 18; ++o) part[(icq * 18 + o) * 64 + p] = acc[o];
    __syncthreads();
    float* ob = ws + OFF_OFFB;
    #pragma unroll
    for (int r = 0; r < 5; ++r) {
        int idx = t + r * 256;
        if (idx < 1152) {
            int o = idx >> 6, p2 = idx & 63;
            float v = part[o * 64 + p2] + part[(18 + o) * 64 + p2]
                    + part[(36 + o) * 64 + p2] + part[(54 + o) * 64 + p2] + boff[o];
            v = tanhf(v) * 5.0f + off_in[(size_t)(b * 18 + o) * HW + row * 64 + p2];
            ob[(size_t)(bg * 18 + o) * HW + row * 64 + p2] = v;
        }
    }
}

// ---- k4: deformable gather + online-softmax attn, 128B-block gathers ----
// XCD-affine: b = blk & 7. grid 4096, block 256; wave = head.
// lane bits[2:0] = pixel (8/wave), bits[5:3] = part (8 x float4 = 128 B block:
// parts 0-3 = k ch[0..16), parts 4-7 = v ch[0..16) of this head's sub-slice).
__global__ __launch_bounds__(256) void k4_attn(
    const float* __restrict__ rpb, float* __restrict__ ws)
{
    __shared__ float rpb_l[NHD * NTAP * HC];
    for (int i = threadIdx.x; i < NHD * NTAP * HC; i += 256) rpb_l[i] = rpb[i];
    __syncthreads();

    const int t = threadIdx.x;
    const int head = __builtin_amdgcn_readfirstlane(t >> 6);
    const int lane = t & 63;
    const int prt  = lane >> 3;          // 0..7
    const int kprt = prt & 3;
    const int pxl  = lane & 7;
    const int b = blockIdx.x & 7;
    const int chunk = blockIdx.x >> 3;   // 0..511
    const int hw = chunk * 8 + pxl;
    const int pix = b * HW + hw;
    const int g = head >> 1, sub = head & 1;
    const int bg = b * 2 + g;
    const float* qt  = ws + OFF_QT;
    const float* kvb = ws + OFF_KT;
    const float* ob  = ws + OFF_OFFB;

    // q fragment: 4 channels for k-parts, zero for v-parts (kills their logit part)
    float4 q4 = *(const float4*)&qt[(size_t)pix * 64 + head * 16 + kprt * 4];
    const float qs = (prt < 4) ? 0.25f : 0.0f;
    float qv[4] = { q4.x * qs, q4.y * qs, q4.z * qs, q4.w * qs };

    float rr[NTAP], cc[NTAP];
    #pragma unroll
    for (int n = 0; n < NTAP; ++n) {
        rr[n] = ob[(size_t)(bg * 18 + 2 * n) * HW + hw];
        cc[n] = ob[(size_t)(bg * 18 + 2 * n + 1) * HW + hw];
    }

    float m = -INFINITY, l = 0.f;
    float oacc[4] = {0.f, 0.f, 0.f, 0.f};
    const size_t kvbase = ((size_t)bg * HW * 2 + sub) * 32 + prt * 4;
    const float* rpb_base = rpb_l + (head * 9) * 16 + kprt * 4;

    #pragma unroll
    for (int n = 0; n < NTAP; ++n) {
        float r = rr[n], c = cc[n];
        float y0f = floorf(r), x0f = floorf(c);
        float fy = r - y0f, fx = c - x0f;
        int iy0 = (int)y0f, ix0 = (int)x0f;
        float wts[4] = { (1.f - fx) * (1.f - fy), fx * (1.f - fy),
                         (1.f - fx) * fy,         fx * fy };
        float a0 = 0.f, a1 = 0.f, a2 = 0.f, a3 = 0.f;
        #pragma unroll
        for (int corner = 0; corner < 4; ++corner) {
            int cxx = ix0 + (corner & 1);
            int cyy = iy0 + (corner >> 1);
            bool vld = ((unsigned)cxx < 64u) && ((unsigned)cyy < 64u);
            float w = vld ? wts[corner] : 0.f;
            int cxc = min(max(cxx, 0), 63);
            int cyc = min(max(cyy, 0), 63);
            float4 kv = *(const float4*)&kvb[kvbase + (size_t)(cyc * 64 + cxc) * 64];
            a0 += w * kv.x; a1 += w * kv.y; a2 += w * kv.z; a3 += w * kv.w;
        }
        float part = qv[0] * (a0 + rpb_base[n * 16 + 0])
                   + qv[1] * (a1 + rpb_base[n * 16 + 1])
                   + qv[2] * (a2 + rpb_base[n * 16 + 2])
                   + qv[3] * (a3 + rpb_base[n * 16 + 3]);
        part += __shfl_xor(part, 8, 64);
        part += __shfl_xor(part, 16, 64);
        part += __shfl_xor(part, 32, 64);   // logit, all lanes
        float nm = fmaxf(m, part);
        float alpha = __expf(m - nm);
        float pexp  = __expf(part - nm);
        l = l * alpha + pexp;
        oacc[0] = oacc[0] * alpha + pexp * a0;
        oacc[1] = oacc[1] * alpha + pexp * a1;
        oacc[2] = oacc[2] * alpha + pexp * a2;
        oacc[3] = oacc[3] * alpha + pexp * a3;
        m = nm;
    }
    if (prt >= 4) {
        float inv = 1.f / l;
        float* ao = ws + OFF_AOT;
        #pragma unroll
        for (int i = 0; i < 4; ++i)
            ao[(size_t)(head * 16 + (prt - 4) * 4 + i) * BHW + pix] = oacc[i] * inv;
    }
}

// ------ k5: proj(64->256)+bias+residual, then cls head (256->80) ----
__global__ __launch_bounds__(256) void k5_proj_cls(
    const float* __restrict__ x, const float* __restrict__ bproj,
    const float* __restrict__ bcls, const float* __restrict__ wsr, float* __restrict__ out)
{
    __shared__ float tmp[DIM * 64];
    const int t = threadIdx.x;
    const int b = blockIdx.x >> 6, row = blockIdx.x & 63;
    const int p = t & 63;
    const int chunk = __builtin_amdgcn_readfirstlane(t >> 6);
    const float* ao  = wsr + OFF_AOT;
    const float* wpT = wsr + OFF_WPT;
    const float* wcT = wsr + OFF_WCT;
    const int pixcol = row * 64 + p;
    const int cb = chunk * 64;

    float acc[64];
    #pragma unroll
    for (int j = 0; j < 64; ++j) acc[j] = 0.f;
    const size_t aob = (size_t)b * HW + pixcol;
    #pragma unroll 4
    for (int cr = 0; cr < 64; ++cr) {
        float av = ao[(size_t)cr * BHW + aob];
        const float* wrow = wpT + cr * 256 + cb;
        #pragma unroll
        for (int j = 0; j < 64; ++j)
            acc[j] += av * wrow[j];
    }
    #pragma unroll
    for (int j = 0; j < 64; ++j) {
        int c = cb + j;
        tmp[c * 64 + p] = acc[j] + bproj[c] + x[(size_t)(b * DIM + c) * HW + pixcol];
    }
    __syncthreads();

    float acc2[20];
    #pragma unroll
    for (int j = 0; j < 20; ++j) acc2[j] = bcls[chunk * 20 + j];
    #pragma unroll 4
    for (int c = 0; c < 256; ++c) {
        float tv = tmp[c * 64 + p];
        const float* wrow = wcT + c * 80 + chunk * 20;
        #pragma unroll
        for (int j = 0; j < 20; ++j)
            acc2[j] += tv * wrow[j];
    }
    #pragma unroll
    for (int j = 0; j < 20; ++j)
        out[(size_t)(b * NCLS + chunk * 20 + j) * HW + pixcol] = acc2[j];
}

extern "C" void kernel_launch(void* const* d_in, const int* in_sizes, int n_in,
                              void* d_out, int out_size, void* d_ws, size_t ws_size,
                              hipStream_t stream)
{
    const float* x     = (const float*)d_in[0];
    const float* off   = (const float*)d_in[1];
    const float* g1    = (const float*)d_in[2];
    const float* b1    = (const float*)d_in[3];
    const float* wqkv  = (const float*)d_in[4];
    const float* wdw   = (const float*)d_in[5];
    const float* g2    = (const float*)d_in[6];
    const float* b2    = (const float*)d_in[7];
    const float* woff  = (const float*)d_in[8];
    const float* boff  = (const float*)d_in[9];
    const float* rpb   = (const float*)d_in[10];
    const float* wproj = (const float*)d_in[11];
    const float* bproj = (const float*)d_in[12];
    const float* wcls  = (const float*)d_in[13];
    const float* bcls  = (const float*)d_in[14];
    float* ws  = (float*)d_ws;
    float* out = (float*)d_out;

    hipLaunchKernelGGL(k0a_transpose, dim3(256), dim3(256), 0, stream, wqkv, g1, wproj, wcls, ws);
    hipLaunchKernelGGL(k0b_ab,        dim3(1),   dim3(192), 0, stream, wqkv, g1, b1, woff, ws);
    hipLaunchKernelGGL(k0c_stats,     dim3(512), dim3(256), 0, stream, x, ws);
    hipLaunchKernelGGL(k1_gemm,       dim3(1024), dim3(256), 0, stream, x, ws);
    hipLaunchKernelGGL(k2_off_feat,   dim3(1024), dim3(256), 0, stream, wdw, g2, b2, ws);
    hipLaunchKernelGGL(k3_pred_off,   dim3(1024), dim3(256), 0, stream, boff, off, ws);
    hipLaunchKernelGGL(k4_attn,       dim3(4096), dim3(256), 0, stream, rpb, ws);
    hipLaunchKernelGGL(k5_proj_cls,   dim3(512), dim3(256), 0, stream, x, bproj, bcls, ws, out);
}

// Round 6
// 313.151 us; speedup vs baseline: 1.0105x; 1.0105x over previous
//
#include <hip/hip_runtime.h>
#include <math.h>

// Problem constants
#define BB   8
#define HW   4096
#define BHW  32768
#define DIM  256
#define CR   64
#define GC   32
#define NHD  4
#define HC   16
#define NTAP 9
#define NCLS 80

// workspace layout (float offsets)
#define OFF_QP   0u          // q planar   [B][64][H][W]            2,097,152
#define OFF_QT   2097152u    // q pix-major[B*HW][64]               2,097,152
#define OFF_KT   4194304u    // KV interleaved [BG][HW][2][32]      4,194,304  (k16|v16 per sub)
#define OFF_T    8388608u    // t planar   [BG][32][H][W]           2,097,152
// --- overlap region: inside OFF_T's span, used only BEFORE k2 writes T ---
#define OFF_WQT  8388608u    // wqkv^T * g1  [256][192]             49,152
#define OFF_AB   8437760u    // A[192], B[192]                      384
#define OFF_STAT 8438144u    // m[32768], rs[32768]                 65,536
// ------------------------------------------------------------------------
#define OFF_OFFB 10485760u   // off planar [BG][18][H][W]           1,179,648
#define OFF_AOT  11665408u   // attn out   [64][B*HW] planar        2,097,152
#define OFF_WPT  13762560u   // wproj^T [64][256]                   16,384
#define OFF_WCT  13778944u   // wcls^T  [256][80]                   20,480
#define OFF_WFT  13799424u   // woff^T  [9][32][18]                 5,184

// ---------------- k0a: weight transposes ----------------
__global__ __launch_bounds__(256) void k0a_transpose(
    const float* __restrict__ wqkv, const float* __restrict__ g1,
    const float* __restrict__ wproj, const float* __restrict__ wcls,
    float* __restrict__ ws)
{
    const int c = blockIdx.x;   // 0..255
    const int t = threadIdx.x;
    if (t < 192) ws[OFF_WQT + c * 192 + t] = wqkv[t * 256 + c] * g1[c];
    if (c < 64)  ws[OFF_WPT + c * 256 + t] = wproj[t * 64 + c];
    if (t < 80)  ws[OFF_WCT + c * 80 + t]  = wcls[t * 256 + c];
}

// ---------------- k0b: A/B LN-fold vectors + woff transpose ----------------
__global__ __launch_bounds__(192) void k0b_ab(
    const float* __restrict__ wqkv, const float* __restrict__ g1,
    const float* __restrict__ b1, const float* __restrict__ woff,
    float* __restrict__ ws)
{
    const int t = threadIdx.x; // 0..191
    float a = 0.f, bb = 0.f;
    for (int c = 0; c < 256; ++c) {
        float w = wqkv[t * 256 + c];
        a += w * g1[c]; bb += w * b1[c];
    }
    ws[OFF_AB + t] = a;
    ws[OFF_AB + 192 + t] = bb;
    for (int pair = t; pair < 288; pair += 192) {
        int wo = pair >> 5, ic = pair & 31;
        for (int o = 0; o < 18; ++o)
            ws[OFF_WFT + (wo * 32 + ic) * 18 + o] = woff[(o * 32 + ic) * 9 + wo];
    }
}

// ---------------- k0c: per-pixel LN stats ----------------
__global__ __launch_bounds__(256) void k0c_stats(
    const float* __restrict__ x, float* __restrict__ ws)
{
    __shared__ float psum[256], psq[256];
    const int t = threadIdx.x;
    const int b = blockIdx.x >> 6, row = blockIdx.x & 63;
    const int p = t & 63, q4 = t >> 6;
    const int colbase = row * 64 + p;
    float s = 0.f, ss = 0.f;
    for (int i = 0; i < 64; ++i) {
        int c = q4 * 64 + i;
        float v = x[(size_t)(b * DIM + c) * HW + colbase];
        s += v; ss += v * v;
    }
    psum[t] = s; psq[t] = ss;
    __syncthreads();
    if (t < 64) {
        float S = psum[t] + psum[64 + t] + psum[128 + t] + psum[192 + t];
        float Q = psq[t] + psq[64 + t] + psq[128 + t] + psq[192 + t];
        float m = S * (1.f / 256.f);
        float v = Q * (1.f / 256.f) - m * m;
        float* stat = ws + OFF_STAT;
        int gp = b * HW + row * 64 + t;
        stat[gp] = m;
        stat[BHW + gp] = rsqrtf(v + 1e-5f);
    }
}

// ---------------- k1: QKV GEMM (LN folded; coalesced epilogue) ----------------
// grid 1024: mhalf=blk>>9 (96 outputs each), (b,row)=blk&511. block 256.
__global__ __launch_bounds__(256) void k1_gemm(
    const float* __restrict__ x, float* __restrict__ ws)
{
    __shared__ float smem[8192];     // 2x 16KB staging; reused as 64x97 transpose tile
    const int t = threadIdx.x;
    const int mhalf = blockIdx.x >> 9;
    const int rb = blockIdx.x & 511;
    const int b = rb >> 6, row = rb & 63;
    const int p = t & 63;
    const int og = __builtin_amdgcn_readfirstlane(t >> 6);
    const int obase = mhalf * 96 + og * 24;
    const float* wqT = ws + OFF_WQT;
    const float* AB  = ws + OFF_AB;
    const float* stat = ws + OFF_STAT;
    const size_t xbase = (size_t)b * DIM * HW + row * 64;

    float acc[24];
    #pragma unroll
    for (int j = 0; j < 24; ++j) acc[j] = 0.f;

    #pragma unroll
    for (int j = 0; j < 4; ++j) {
        int idx4 = t + j * 256;
        int c = idx4 >> 4, p4 = (idx4 & 15) << 2;
        float4 v = *(const float4*)&x[xbase + (size_t)c * HW + p4];
        *(float4*)&smem[c * 64 + p4] = v;
    }
    __syncthreads();

    for (int kt = 0; kt < 4; ++kt) {
        const int cur = kt & 1;
        float4 pf[4];
        if (kt < 3) {
            #pragma unroll
            for (int j = 0; j < 4; ++j) {
                int idx4 = t + j * 256;
                int c = idx4 >> 4, p4 = (idx4 & 15) << 2;
                pf[j] = *(const float4*)&x[xbase + (size_t)((kt + 1) * 64 + c) * HW + p4];
            }
        }
        const float* wb = wqT + (size_t)kt * 64 * 192 + obase;
        #pragma unroll 8
        for (int c = 0; c < 64; ++c) {
            float xv = smem[cur * 4096 + c * 64 + p];
            #pragma unroll
            for (int j = 0; j < 24; ++j)
                acc[j] += wb[c * 192 + j] * xv;
        }
        if (kt < 3) {
            #pragma unroll
            for (int j = 0; j < 4; ++j) {
                int idx4 = t + j * 256;
                int c = idx4 >> 4, p4 = (idx4 & 15) << 2;
                *(float4*)&smem[(cur ^ 1) * 4096 + c * 64 + p4] = pf[j];
            }
            __syncthreads();
        }
    }
    __syncthreads();

    const int colbase = row * 64 + p;
    const int gp = b * HW + colbase;
    const float m = stat[gp], rsv = stat[BHW + gp];
    #pragma unroll
    for (int j = 0; j < 24; ++j) {
        int o = obase + j;
        smem[p * 97 + og * 24 + j] = rsv * (acc[j] - m * AB[o]) + AB[192 + o];
    }
    __syncthreads();

    float* qp  = ws + OFF_QP;
    float* qt  = ws + OFF_QT;
    float* kvb = ws + OFF_KT;
    const int colrow = row * 64;
    if (mhalf == 0) {
        // q planar
        #pragma unroll
        for (int it = 0; it < 16; ++it) {
            int idx = it * 256 + t;
            int o = idx >> 6, px = idx & 63;
            qp[(size_t)(b * 64 + o) * HW + colrow + px] = smem[px * 97 + o];
        }
        // q pixel-major
        #pragma unroll
        for (int it = 0; it < 16; ++it) {
            int idx = it * 256 + t;
            int px = idx >> 6, o = idx & 63;
            qt[((size_t)(b * HW + colrow + px)) * 64 + o] = smem[px * 97 + o];
        }
        // k of bg=2b (tile cols 64..95), slot j
        #pragma unroll
        for (int it = 0; it < 8; ++it) {
            int idx = it * 256 + t;
            int px = idx >> 5, sub = (idx >> 4) & 1, j = idx & 15;
            kvb[(((size_t)(2 * b) * HW + colrow + px) * 2 + sub) * 32 + j]
                = smem[px * 97 + 64 + sub * 16 + j];
        }
    } else {
        // k of bg=2b+1 (cols 0..31), slot j
        #pragma unroll
        for (int it = 0; it < 8; ++it) {
            int idx = it * 256 + t;
            int px = idx >> 5, sub = (idx >> 4) & 1, j = idx & 15;
            kvb[(((size_t)(2 * b + 1) * HW + colrow + px) * 2 + sub) * 32 + j]
                = smem[px * 97 + sub * 16 + j];
        }
        // v of bg=2b (cols 32..63), slot 16+j
        #pragma unroll
        for (int it = 0; it < 8; ++it) {
            int idx = it * 256 + t;
            int px = idx >> 5, sub = (idx >> 4) & 1, j = idx & 15;
            kvb[(((size_t)(2 * b) * HW + colrow + px) * 2 + sub) * 32 + 16 + j]
                = smem[px * 97 + 32 + sub * 16 + j];
        }
        // v of bg=2b+1 (cols 64..95), slot 16+j
        #pragma unroll
        for (int it = 0; it < 8; ++it) {
            int idx = it * 256 + t;
            int px = idx >> 5, sub = (idx >> 4) & 1, j = idx & 15;
            kvb[(((size_t)(2 * b + 1) * HW + colrow + px) * 2 + sub) * 32 + 16 + j]
                = smem[px * 97 + 64 + sub * 16 + j];
        }
    }
}

// ------- k2: depthwise 3x3 + LN(32) + GELU, channel-split across waves -------
__global__ __launch_bounds__(256) void k2_off_feat(
    const float* __restrict__ wdw, const float* __restrict__ g2, const float* __restrict__ b2,
    float* __restrict__ ws)
{
    __shared__ float rsum[4][64], rsq[4][64], smv[64], srv[64];
    const int t = threadIdx.x;
    const int bg = blockIdx.x >> 6, row = blockIdx.x & 63;
    const int p = t & 63;
    const int cq = __builtin_amdgcn_readfirstlane(t >> 6);
    const int b = bg >> 1, g = bg & 1;
    const float* qp = ws + OFF_QP;
    float vals[8];
    float s = 0.f, ss = 0.f;
    #pragma unroll
    for (int i = 0; i < 8; ++i) {
        int ch = cq * 8 + i;
        const float* plane = qp + (size_t)(b * 64 + g * 32 + ch) * HW;
        float a = 0.f;
        #pragma unroll
        for (int dy = 0; dy < 3; ++dy) {
            int y = row + dy - 1;
            if ((unsigned)y >= 64u) continue;
            #pragma unroll
            for (int dx = 0; dx < 3; ++dx) {
                int xx = p + dx - 1;
                bool vld = (unsigned)xx < 64u;
                float q = plane[y * 64 + (vld ? xx : 0)];
                a += (vld ? q : 0.f) * wdw[ch * 9 + dy * 3 + dx];
            }
        }
        vals[i] = a; s += a; ss += a * a;
    }
    rsum[cq][p] = s; rsq[cq][p] = ss;
    __syncthreads();
    if (t < 64) {
        float S = rsum[0][t] + rsum[1][t] + rsum[2][t] + rsum[3][t];
        float Q = rsq[0][t] + rsq[1][t] + rsq[2][t] + rsq[3][t];
        float m = S * (1.f / 32.f);
        float v = Q * (1.f / 32.f) - m * m;
        smv[t] = m; srv[t] = rsqrtf(v + 1e-5f);
    }
    __syncthreads();
    float m = smv[p], rv = srv[p];
    float* tb = ws + OFF_T;
    #pragma unroll
    for (int i = 0; i < 8; ++i) {
        int ch = cq * 8 + i;
        float u = (vals[i] - m) * rv * g2[ch] + b2[ch];
        float ge = 0.5f * u * (1.f + erff(u * 0.70710678118654752f));
        tb[(size_t)(bg * 32 + ch) * HW + row * 64 + p] = ge;
    }
}

// ------- k3: 3x3 conv 32->18 + tanh*5 + base offset, ic-split across waves -------
__global__ __launch_bounds__(256) void k3_pred_off(
    const float* __restrict__ boff, const float* __restrict__ off_in,
    float* __restrict__ ws)
{
    __shared__ float part[4 * 18 * 64];
    const int t = threadIdx.x;
    const int bg = blockIdx.x >> 6, row = blockIdx.x & 63;
    const int p = t & 63;
    const int icq = __builtin_amdgcn_readfirstlane(t >> 6);
    const int b = bg >> 1;
    const float* tb = ws + OFF_T;
    const float* wfT = ws + OFF_WFT;
    float acc[18];
    #pragma unroll
    for (int o = 0; o < 18; ++o) acc[o] = 0.f;
    #pragma unroll
    for (int dy = 0; dy < 3; ++dy) {
        int y = row + dy - 1;
        if ((unsigned)y >= 64u) continue;
        #pragma unroll
        for (int dx = 0; dx < 3; ++dx) {
            int xx = p + dx - 1;
            bool vld = (unsigned)xx < 64u;
            int xc = vld ? xx : 0;
            int wo = dy * 3 + dx;
            #pragma unroll
            for (int i = 0; i < 8; ++i) {
                int ic = icq * 8 + i;
                float tv = tb[(size_t)(bg * 32 + ic) * HW + y * 64 + xc];
                tv = vld ? tv : 0.f;
                const float* wrow = wfT + (wo * 32 + ic) * 18;
                #pragma unroll
                for (int o = 0; o < 18; ++o)
                    acc[o] += tv * wrow[o];
            }
        }
    }
    #pragma unroll
    for (int o = 0; o < 18; ++o) part[(icq * 18 + o) * 64 + p] = acc[o];
    __syncthreads();
    float* ob = ws + OFF_OFFB;
    #pragma unroll
    for (int r = 0; r < 5; ++r) {
        int idx = t + r * 256;
        if (idx < 1152) {
            int o = idx >> 6, p2 = idx & 63;
            float v = part[o * 64 + p2] + part[(18 + o) * 64 + p2]
                    + part[(36 + o) * 64 + p2] + part[(54 + o) * 64 + p2] + boff[o];
            v = tanhf(v) * 5.0f + off_in[(size_t)(b * 18 + o) * HW + row * 64 + p2];
            ob[(size_t)(bg * 18 + o) * HW + row * 64 + p2] = v;
        }
    }
}

// ---- k4: deformable gather + softmax attn, ILP over taps (no serial chain) ----
// XCD-affine: b = blk & 7. grid 4096, block 256; wave = head.
// lane bits[2:0] = pixel (8/wave), bits[5:3] = part (parts 0-3 = k ch, 4-7 = v ch).
// Phase 1: all 9 tap gathers+logits independent (ILP hides L2 latency).
// Phase 2: flat softmax. Phase 3: weighted V sum from registers.
__global__ __launch_bounds__(256) void k4_attn(
    const float* __restrict__ rpb, float* __restrict__ ws)
{
    __shared__ float rpb_l[NHD * NTAP * HC];
    for (int i = threadIdx.x; i < NHD * NTAP * HC; i += 256) rpb_l[i] = rpb[i];
    __syncthreads();

    const int t = threadIdx.x;
    const int head = __builtin_amdgcn_readfirstlane(t >> 6);
    const int lane = t & 63;
    const int prt  = lane >> 3;          // 0..7
    const int kprt = prt & 3;
    const int pxl  = lane & 7;
    const int b = blockIdx.x & 7;
    const int chunk = blockIdx.x >> 3;   // 0..511
    const int hw = chunk * 8 + pxl;
    const int pix = b * HW + hw;
    const int g = head >> 1, sub = head & 1;
    const int bg = b * 2 + g;
    const float* qt  = ws + OFF_QT;
    const float* kvb = ws + OFF_KT;
    const float* ob  = ws + OFF_OFFB;

    // q fragment: 4 channels for k-parts, zero for v-parts (kills their logit part)
    float4 q4 = *(const float4*)&qt[(size_t)pix * 64 + head * 16 + kprt * 4];
    const float qs = (prt < 4) ? 0.25f : 0.0f;
    float qv[4] = { q4.x * qs, q4.y * qs, q4.z * qs, q4.w * qs };

    float rr[NTAP], cc[NTAP];
    #pragma unroll
    for (int n = 0; n < NTAP; ++n) {
        rr[n] = ob[(size_t)(bg * 18 + 2 * n) * HW + hw];
        cc[n] = ob[(size_t)(bg * 18 + 2 * n + 1) * HW + hw];
    }

    const size_t kvbase = ((size_t)bg * HW * 2 + sub) * 32 + prt * 4;
    const float* rpb_base = rpb_l + (head * 9) * 16 + kprt * 4;

    float av[NTAP][4];     // gathered fragment per tap (k-slice on k-lanes, v-slice on v-lanes)
    float logit[NTAP];

    // ---- Phase 1: independent tap bodies ----
    #pragma unroll
    for (int n = 0; n < NTAP; ++n) {
        float r = rr[n], c = cc[n];
        float y0f = floorf(r), x0f = floorf(c);
        float fy = r - y0f, fx = c - x0f;
        int iy0 = (int)y0f, ix0 = (int)x0f;
        float wts[4] = { (1.f - fx) * (1.f - fy), fx * (1.f - fy),
                         (1.f - fx) * fy,         fx * fy };
        float a0 = 0.f, a1 = 0.f, a2 = 0.f, a3 = 0.f;
        #pragma unroll
        for (int corner = 0; corner < 4; ++corner) {
            int cxx = ix0 + (corner & 1);
            int cyy = iy0 + (corner >> 1);
            bool vld = ((unsigned)cxx < 64u) && ((unsigned)cyy < 64u);
            float w = vld ? wts[corner] : 0.f;
            int cxc = min(max(cxx, 0), 63);
            int cyc = min(max(cyy, 0), 63);
            float4 kv = *(const float4*)&kvb[kvbase + (size_t)(cyc * 64 + cxc) * 64];
            a0 += w * kv.x; a1 += w * kv.y; a2 += w * kv.z; a3 += w * kv.w;
        }
        av[n][0] = a0; av[n][1] = a1; av[n][2] = a2; av[n][3] = a3;
        float part = qv[0] * (a0 + rpb_base[n * 16 + 0])
                   + qv[1] * (a1 + rpb_base[n * 16 + 1])
                   + qv[2] * (a2 + rpb_base[n * 16 + 2])
                   + qv[3] * (a3 + rpb_base[n * 16 + 3]);
        part += __shfl_xor(part, 8, 64);
        part += __shfl_xor(part, 16, 64);
        part += __shfl_xor(part, 32, 64);   // logit, all lanes
        logit[n] = part;
    }

    // ---- Phase 2: flat softmax over 9 ----
    float m = logit[0];
    #pragma unroll
    for (int n = 1; n < NTAP; ++n) m = fmaxf(m, logit[n]);
    float l = 0.f;
    #pragma unroll
    for (int n = 0; n < NTAP; ++n) { logit[n] = __expf(logit[n] - m); l += logit[n]; }
    float inv = 1.f / l;

    // ---- Phase 3: weighted V sum (valid on v-lanes) ----
    float o0 = 0.f, o1 = 0.f, o2 = 0.f, o3 = 0.f;
    #pragma unroll
    for (int n = 0; n < NTAP; ++n) {
        o0 += logit[n] * av[n][0];
        o1 += logit[n] * av[n][1];
        o2 += logit[n] * av[n][2];
        o3 += logit[n] * av[n][3];
    }
    if (prt >= 4) {
        float* ao = ws + OFF_AOT;
        const int cb = head * 16 + (prt - 4) * 4;
        ao[(size_t)(cb + 0) * BHW + pix] = o0 * inv;
        ao[(size_t)(cb + 1) * BHW + pix] = o1 * inv;
        ao[(size_t)(cb + 2) * BHW + pix] = o2 * inv;
        ao[(size_t)(cb + 3) * BHW + pix] = o3 * inv;
    }
}

// ------ k5: proj(64->256)+bias+residual, then cls head (256->80) ----
__global__ __launch_bounds__(256) void k5_proj_cls(
    const float* __restrict__ x, const float* __restrict__ bproj,
    const float* __restrict__ bcls, const float* __restrict__ wsr, float* __restrict__ out)
{
    __shared__ float tmp[DIM * 64];
    const int t = threadIdx.x;
    const int b = blockIdx.x >> 6, row = blockIdx.x & 63;
    const int p = t & 63;
    const int chunk = __builtin_amdgcn_readfirstlane(t >> 6);
    const float* ao  = wsr + OFF_AOT;
    const float* wpT = wsr + OFF_WPT;
    const float* wcT = wsr + OFF_WCT;
    const int pixcol = row * 64 + p;
    const int cb = chunk * 64;

    float acc[64];
    #pragma unroll
    for (int j = 0; j < 64; ++j) acc[j] = 0.f;
    const size_t aob = (size_t)b * HW + pixcol;
    #pragma unroll 4
    for (int cr = 0; cr < 64; ++cr) {
        float av = ao[(size_t)cr * BHW + aob];
        const float* wrow = wpT + cr * 256 + cb;
        #pragma unroll
        for (int j = 0; j < 64; ++j)
            acc[j] += av * wrow[j];
    }
    #pragma unroll
    for (int j = 0; j < 64; ++j) {
        int c = cb + j;
        tmp[c * 64 + p] = acc[j] + bproj[c] + x[(size_t)(b * DIM + c) * HW + pixcol];
    }
    __syncthreads();

    float acc2[20];
    #pragma unroll
    for (int j = 0; j < 20; ++j) acc2[j] = bcls[chunk * 20 + j];
    #pragma unroll 4
    for (int c = 0; c < 256; ++c) {
        float tv = tmp[c * 64 + p];
        const float* wrow = wcT + c * 80 + chunk * 20;
        #pragma unroll
        for (int j = 0; j < 20; ++j)
            acc2[j] += tv * wrow[j];
    }
    #pragma unroll
    for (int j = 0; j < 20; ++j)
        out[(size_t)(b * NCLS + chunk * 20 + j) * HW + pixcol] = acc2[j];
}

extern "C" void kernel_launch(void* const* d_in, const int* in_sizes, int n_in,
                              void* d_out, int out_size, void* d_ws, size_t ws_size,
                              hipStream_t stream)
{
    const float* x     = (const float*)d_in[0];
    const float* off   = (const float*)d_in[1];
    const float* g1    = (const float*)d_in[2];
    const float* b1    = (const float*)d_in[3];
    const float* wqkv  = (const float*)d_in[4];
    const float* wdw   = (const float*)d_in[5];
    const float* g2    = (const float*)d_in[6];
    const float* b2    = (const float*)d_in[7];
    const float* woff  = (const float*)d_in[8];
    const float* boff  = (const float*)d_in[9];
    const float* rpb   = (const float*)d_in[10];
    const float* wproj = (const float*)d_in[11];
    const float* bproj = (const float*)d_in[12];
    const float* wcls  = (const float*)d_in[13];
    const float* bcls  = (const float*)d_in[14];
    float* ws  = (float*)d_ws;
    float* out = (float*)d_out;

    hipLaunchKernelGGL(k0a_transpose, dim3(256), dim3(256), 0, stream, wqkv, g1, wproj, wcls, ws);
    hipLaunchKernelGGL(k0b_ab,        dim3(1),   dim3(192), 0, stream, wqkv, g1, b1, woff, ws);
    hipLaunchKernelGGL(k0c_stats,     dim3(512), dim3(256), 0, stream, x, ws);
    hipLaunchKernelGGL(k1_gemm,       dim3(1024), dim3(256), 0, stream, x, ws);
    hipLaunchKernelGGL(k2_off_feat,   dim3(1024), dim3(256), 0, stream, wdw, g2, b2, ws);
    hipLaunchKernelGGL(k3_pred_off,   dim3(1024), dim3(256), 0, stream, boff, off, ws);
    hipLaunchKernelGGL(k4_attn,       dim3(4096), dim3(256), 0, stream, rpb, ws);
    hipLaunchKernelGGL(k5_proj_cls,   dim3(512), dim3(256), 0, stream, x, bproj, bcls, ws, out);
}

// Round 7
// 279.334 us; speedup vs baseline: 1.1329x; 1.1211x over previous
//
#include <hip/hip_runtime.h>
#include <hip/hip_fp16.h>
#include <math.h>

// Problem constants
#define BB   8
#define HW   4096
#define BHW  32768
#define DIM  256
#define CR   64
#define GC   32
#define NHD  4
#define HC   16
#define NTAP 9
#define NCLS 80

// workspace layout (float offsets)
#define OFF_QP   0u          // q planar   [B][64][H][W] fp32       2,097,152
#define OFF_QT   2097152u    // q pix-major[B*HW][64] fp16          1,048,576 (floats of space)
#define OFF_KT   4194304u    // KV fp16 [BG][HW][2 sub][k16|v16]    2,097,152 (floats of space)
#define OFF_T    8388608u    // t planar   [BG][32][H][W]           2,097,152
// --- overlap region: inside OFF_T's span, used only BEFORE k2 writes T ---
#define OFF_WQT  8388608u    // wqkv^T * g1  [256][192]             49,152
#define OFF_AB   8437760u    // A[192], B[192]                      384
#define OFF_STAT 8438144u    // m[32768], rs[32768]                 65,536
// ------------------------------------------------------------------------
#define OFF_OFFB 10485760u   // off planar [BG][18][H][W]           1,179,648
#define OFF_AOT  11665408u   // attn out   [64][B*HW] planar fp32   2,097,152
#define OFF_WPT  13762560u   // wproj^T [64][256]                   16,384
#define OFF_WCT  13778944u   // wcls^T  [256][80]                   20,480
#define OFF_WFT  13799424u   // woff^T  [9][32][18]                 5,184

// ---------------- k0a: weight transposes ----------------
__global__ __launch_bounds__(256) void k0a_transpose(
    const float* __restrict__ wqkv, const float* __restrict__ g1,
    const float* __restrict__ wproj, const float* __restrict__ wcls,
    float* __restrict__ ws)
{
    const int c = blockIdx.x;   // 0..255
    const int t = threadIdx.x;
    if (t < 192) ws[OFF_WQT + c * 192 + t] = wqkv[t * 256 + c] * g1[c];
    if (c < 64)  ws[OFF_WPT + c * 256 + t] = wproj[t * 64 + c];
    if (t < 80)  ws[OFF_WCT + c * 80 + t]  = wcls[t * 256 + c];
}

// ---------------- k0b: A/B LN-fold vectors + woff transpose ----------------
__global__ __launch_bounds__(192) void k0b_ab(
    const float* __restrict__ wqkv, const float* __restrict__ g1,
    const float* __restrict__ b1, const float* __restrict__ woff,
    float* __restrict__ ws)
{
    const int t = threadIdx.x; // 0..191
    float a = 0.f, bb = 0.f;
    for (int c = 0; c < 256; ++c) {
        float w = wqkv[t * 256 + c];
        a += w * g1[c]; bb += w * b1[c];
    }
    ws[OFF_AB + t] = a;
    ws[OFF_AB + 192 + t] = bb;
    for (int pair = t; pair < 288; pair += 192) {
        int wo = pair >> 5, ic = pair & 31;
        for (int o = 0; o < 18; ++o)
            ws[OFF_WFT + (wo * 32 + ic) * 18 + o] = woff[(o * 32 + ic) * 9 + wo];
    }
}

// ---------------- k0c: per-pixel LN stats ----------------
__global__ __launch_bounds__(256) void k0c_stats(
    const float* __restrict__ x, float* __restrict__ ws)
{
    __shared__ float psum[256], psq[256];
    const int t = threadIdx.x;
    const int b = blockIdx.x >> 6, row = blockIdx.x & 63;
    const int p = t & 63, q4 = t >> 6;
    const int colbase = row * 64 + p;
    float s = 0.f, ss = 0.f;
    for (int i = 0; i < 64; ++i) {
        int c = q4 * 64 + i;
        float v = x[(size_t)(b * DIM + c) * HW + colbase];
        s += v; ss += v * v;
    }
    psum[t] = s; psq[t] = ss;
    __syncthreads();
    if (t < 64) {
        float S = psum[t] + psum[64 + t] + psum[128 + t] + psum[192 + t];
        float Q = psq[t] + psq[64 + t] + psq[128 + t] + psq[192 + t];
        float m = S * (1.f / 256.f);
        float v = Q * (1.f / 256.f) - m * m;
        float* stat = ws + OFF_STAT;
        int gp = b * HW + row * 64 + t;
        stat[gp] = m;
        stat[BHW + gp] = rsqrtf(v + 1e-5f);
    }
}

// ---------------- k1: QKV GEMM (LN folded; fp16 q/KV epilogue) ----------------
// grid 1024: mhalf=blk>>9 (96 outputs each), (b,row)=blk&511. block 256.
__global__ __launch_bounds__(256) void k1_gemm(
    const float* __restrict__ x, float* __restrict__ ws)
{
    __shared__ float smem[8192];     // 2x 16KB staging; reused as 64x97 transpose tile
    const int t = threadIdx.x;
    const int mhalf = blockIdx.x >> 9;
    const int rb = blockIdx.x & 511;
    const int b = rb >> 6, row = rb & 63;
    const int p = t & 63;
    const int og = __builtin_amdgcn_readfirstlane(t >> 6);
    const int obase = mhalf * 96 + og * 24;
    const float* wqT = ws + OFF_WQT;
    const float* AB  = ws + OFF_AB;
    const float* stat = ws + OFF_STAT;
    const size_t xbase = (size_t)b * DIM * HW + row * 64;

    float acc[24];
    #pragma unroll
    for (int j = 0; j < 24; ++j) acc[j] = 0.f;

    #pragma unroll
    for (int j = 0; j < 4; ++j) {
        int idx4 = t + j * 256;
        int c = idx4 >> 4, p4 = (idx4 & 15) << 2;
        float4 v = *(const float4*)&x[xbase + (size_t)c * HW + p4];
        *(float4*)&smem[c * 64 + p4] = v;
    }
    __syncthreads();

    for (int kt = 0; kt < 4; ++kt) {
        const int cur = kt & 1;
        float4 pf[4];
        if (kt < 3) {
            #pragma unroll
            for (int j = 0; j < 4; ++j) {
                int idx4 = t + j * 256;
                int c = idx4 >> 4, p4 = (idx4 & 15) << 2;
                pf[j] = *(const float4*)&x[xbase + (size_t)((kt + 1) * 64 + c) * HW + p4];
            }
        }
        const float* wb = wqT + (size_t)kt * 64 * 192 + obase;
        #pragma unroll 8
        for (int c = 0; c < 64; ++c) {
            float xv = smem[cur * 4096 + c * 64 + p];
            #pragma unroll
            for (int j = 0; j < 24; ++j)
                acc[j] += wb[c * 192 + j] * xv;
        }
        if (kt < 3) {
            #pragma unroll
            for (int j = 0; j < 4; ++j) {
                int idx4 = t + j * 256;
                int c = idx4 >> 4, p4 = (idx4 & 15) << 2;
                *(float4*)&smem[(cur ^ 1) * 4096 + c * 64 + p4] = pf[j];
            }
            __syncthreads();
        }
    }
    __syncthreads();

    const int colbase = row * 64 + p;
    const int gp = b * HW + colbase;
    const float m = stat[gp], rsv = stat[BHW + gp];
    #pragma unroll
    for (int j = 0; j < 24; ++j) {
        int o = obase + j;
        smem[p * 97 + og * 24 + j] = rsv * (acc[j] - m * AB[o]) + AB[192 + o];
    }
    __syncthreads();

    float*  qp  = ws + OFF_QP;
    __half* qth = (__half*)(ws + OFF_QT);
    __half* kvh = (__half*)(ws + OFF_KT);
    const int colrow = row * 64;
    if (mhalf == 0) {
        // q planar fp32 (k2 input)
        #pragma unroll
        for (int it = 0; it < 16; ++it) {
            int idx = it * 256 + t;
            int o = idx >> 6, px = idx & 63;
            qp[(size_t)(b * 64 + o) * HW + colrow + px] = smem[px * 97 + o];
        }
        // q pixel-major fp16 (k4 input)
        #pragma unroll
        for (int it = 0; it < 16; ++it) {
            int idx = it * 256 + t;
            int px = idx >> 6, o = idx & 63;
            qth[(size_t)(b * HW + colrow + px) * 64 + o] = __float2half(smem[px * 97 + o]);
        }
        // k of bg=2b (tile cols 64..95)
        #pragma unroll
        for (int it = 0; it < 8; ++it) {
            int idx = it * 256 + t;
            int px = idx >> 5, ch32 = idx & 31;
            int s = ch32 >> 4, ch = ch32 & 15;
            kvh[(size_t)((2 * b) * HW + colrow + px) * 64 + s * 32 + ch]
                = __float2half(smem[px * 97 + 64 + ch32]);
        }
    } else {
        // k of bg=2b+1 (cols 0..31)
        #pragma unroll
        for (int it = 0; it < 8; ++it) {
            int idx = it * 256 + t;
            int px = idx >> 5, ch32 = idx & 31;
            int s = ch32 >> 4, ch = ch32 & 15;
            kvh[(size_t)((2 * b + 1) * HW + colrow + px) * 64 + s * 32 + ch]
                = __float2half(smem[px * 97 + ch32]);
        }
        // v of bg=2b (cols 32..63)
        #pragma unroll
        for (int it = 0; it < 8; ++it) {
            int idx = it * 256 + t;
            int px = idx >> 5, ch32 = idx & 31;
            int s = ch32 >> 4, ch = ch32 & 15;
            kvh[(size_t)((2 * b) * HW + colrow + px) * 64 + s * 32 + 16 + ch]
                = __float2half(smem[px * 97 + 32 + ch32]);
        }
        // v of bg=2b+1 (cols 64..95)
        #pragma unroll
        for (int it = 0; it < 8; ++it) {
            int idx = it * 256 + t;
            int px = idx >> 5, ch32 = idx & 31;
            int s = ch32 >> 4, ch = ch32 & 15;
            kvh[(size_t)((2 * b + 1) * HW + colrow + px) * 64 + s * 32 + 16 + ch]
                = __float2half(smem[px * 97 + 64 + ch32]);
        }
    }
}

// ------- k2: depthwise 3x3 + LN(32) + GELU, channel-split across waves -------
__global__ __launch_bounds__(256) void k2_off_feat(
    const float* __restrict__ wdw, const float* __restrict__ g2, const float* __restrict__ b2,
    float* __restrict__ ws)
{
    __shared__ float rsum[4][64], rsq[4][64], smv[64], srv[64];
    const int t = threadIdx.x;
    const int bg = blockIdx.x >> 6, row = blockIdx.x & 63;
    const int p = t & 63;
    const int cq = __builtin_amdgcn_readfirstlane(t >> 6);
    const int b = bg >> 1, g = bg & 1;
    const float* qp = ws + OFF_QP;
    float vals[8];
    float s = 0.f, ss = 0.f;
    #pragma unroll
    for (int i = 0; i < 8; ++i) {
        int ch = cq * 8 + i;
        const float* plane = qp + (size_t)(b * 64 + g * 32 + ch) * HW;
        float a = 0.f;
        #pragma unroll
        for (int dy = 0; dy < 3; ++dy) {
            int y = row + dy - 1;
            if ((unsigned)y >= 64u) continue;
            #pragma unroll
            for (int dx = 0; dx < 3; ++dx) {
                int xx = p + dx - 1;
                bool vld = (unsigned)xx < 64u;
                float q = plane[y * 64 + (vld ? xx : 0)];
                a += (vld ? q : 0.f) * wdw[ch * 9 + dy * 3 + dx];
            }
        }
        vals[i] = a; s += a; ss += a * a;
    }
    rsum[cq][p] = s; rsq[cq][p] = ss;
    __syncthreads();
    if (t < 64) {
        float S = rsum[0][t] + rsum[1][t] + rsum[2][t] + rsum[3][t];
        float Q = rsq[0][t] + rsq[1][t] + rsq[2][t] + rsq[3][t];
        float m = S * (1.f / 32.f);
        float v = Q * (1.f / 32.f) - m * m;
        smv[t] = m; srv[t] = rsqrtf(v + 1e-5f);
    }
    __syncthreads();
    float m = smv[p], rv = srv[p];
    float* tb = ws + OFF_T;
    #pragma unroll
    for (int i = 0; i < 8; ++i) {
        int ch = cq * 8 + i;
        float u = (vals[i] - m) * rv * g2[ch] + b2[ch];
        float ge = 0.5f * u * (1.f + erff(u * 0.70710678118654752f));
        tb[(size_t)(bg * 32 + ch) * HW + row * 64 + p] = ge;
    }
}

// ------- k3: 3x3 conv 32->18 + tanh*5 + base offset, ic-split across waves -------
__global__ __launch_bounds__(256) void k3_pred_off(
    const float* __restrict__ boff, const float* __restrict__ off_in,
    float* __restrict__ ws)
{
    __shared__ float part[4 * 18 * 64];
    const int t = threadIdx.x;
    const int bg = blockIdx.x >> 6, row = blockIdx.x & 63;
    const int p = t & 63;
    const int icq = __builtin_amdgcn_readfirstlane(t >> 6);
    const int b = bg >> 1;
    const float* tb = ws + OFF_T;
    const float* wfT = ws + OFF_WFT;
    float acc[18];
    #pragma unroll
    for (int o = 0; o < 18; ++o) acc[o] = 0.f;
    #pragma unroll
    for (int dy = 0; dy < 3; ++dy) {
        int y = row + dy - 1;
        if ((unsigned)y >= 64u) continue;
        #pragma unroll
        for (int dx = 0; dx < 3; ++dx) {
            int xx = p + dx - 1;
            bool vld = (unsigned)xx < 64u;
            int xc = vld ? xx : 0;
            int wo = dy * 3 + dx;
            #pragma unroll
            for (int i = 0; i < 8; ++i) {
                int ic = icq * 8 + i;
                float tv = tb[(size_t)(bg * 32 + ic) * HW + y * 64 + xc];
                tv = vld ? tv : 0.f;
                const float* wrow = wfT + (wo * 32 + ic) * 18;
                #pragma unroll
                for (int o = 0; o < 18; ++o)
                    acc[o] += tv * wrow[o];
            }
        }
    }
    #pragma unroll
    for (int o = 0; o < 18; ++o) part[(icq * 18 + o) * 64 + p] = acc[o];
    __syncthreads();
    float* ob = ws + OFF_OFFB;
    #pragma unroll
    for (int r = 0; r < 5; ++r) {
        int idx = t + r * 256;
        if (idx < 1152) {
            int o = idx >> 6, p2 = idx & 63;
            float v = part[o * 64 + p2] + part[(18 + o) * 64 + p2]
                    + part[(36 + o) * 64 + p2] + part[(54 + o) * 64 + p2] + boff[o];
            v = tanhf(v) * 5.0f + off_in[(size_t)(b * 18 + o) * HW + row * 64 + p2];
            ob[(size_t)(bg * 18 + o) * HW + row * 64 + p2] = v;
        }
    }
}

// ---- k4: deformable gather + softmax attn, fp16 KV, one wave = one group ----
// XCD-affine: b = blk & 7. grid 2048, block 256.
// wave w: g = w&1, pxhalf = w>>1. lane: pxl = lane&7, prt = lane>>3 with
// prt = sub*4 + half*2 + j  (half: 0=k, 1=v; j: 8-ch slice). Each lane loads
// one float4 = 8 fp16 channels; a wave's 64 lanes cover 8 complete 128 B
// pixel blocks per gather instruction (both subs, k and v).
__global__ __launch_bounds__(256, 2) void k4_attn(
    const float* __restrict__ rpb, float* __restrict__ ws)
{
    __shared__ float rpb_l[NHD * NTAP * HC]; // 576 floats
    for (int i = threadIdx.x; i < NHD * NTAP * HC; i += 256) rpb_l[i] = rpb[i];
    __syncthreads();

    const int t = threadIdx.x;
    const int wave = __builtin_amdgcn_readfirstlane(t >> 6);
    const int g = wave & 1, pxh = wave >> 1;
    const int lane = t & 63;
    const int pxl = lane & 7;
    const int prt = lane >> 3;
    const int s    = prt >> 2;
    const int half = (prt >> 1) & 1;
    const int j    = prt & 1;
    const int b = blockIdx.x & 7;
    const int chunk = blockIdx.x >> 3;          // 0..255
    const int hw = chunk * 16 + pxh * 8 + pxl;
    const int pix = b * HW + hw;
    const int bg = b * 2 + g;
    const int head = g * 2 + s;

    const __half* qth = (const __half*)(ws + OFF_QT);
    const __half* kvh = (const __half*)(ws + OFF_KT);
    const float*  ob  = ws + OFF_OFFB;

    // q: 8 fp16 ch -> fp32, scaled; zero on v-lanes (kills their logit partial)
    union F4H { float4 f; __half2 h[4]; };
    F4H qld;
    qld.f = *(const float4*)&qth[(size_t)pix * 64 + g * 32 + s * 16 + j * 8];
    const float qs = half ? 0.0f : 0.25f;
    float qv[8];
    #pragma unroll
    for (int i = 0; i < 4; ++i) {
        float2 q2 = __half22float2(qld.h[i]);
        qv[2 * i] = q2.x * qs; qv[2 * i + 1] = q2.y * qs;
    }

    const float4* rb4 = (const float4*)(rpb_l + head * (NTAP * HC) + j * 8);
    const __half* kvp = kvh + (size_t)(bg * HW) * 64 + prt * 8;

    __half2 av[NTAP][4];
    float logit[NTAP];

    // ---- Phase 1: 9 independent tap gathers + logits ----
    #pragma unroll
    for (int n = 0; n < NTAP; ++n) {
        float r = ob[(size_t)(bg * 18 + 2 * n) * HW + hw];
        float c = ob[(size_t)(bg * 18 + 2 * n + 1) * HW + hw];
        float y0f = floorf(r), x0f = floorf(c);
        float fy = r - y0f, fx = c - x0f;
        int iy0 = (int)y0f, ix0 = (int)x0f;
        float wts[4] = { (1.f - fx) * (1.f - fy), fx * (1.f - fy),
                         (1.f - fx) * fy,         fx * fy };
        __half2 acc0 = __float2half2_rn(0.f), acc1 = acc0, acc2 = acc0, acc3 = acc0;
        #pragma unroll
        for (int corner = 0; corner < 4; ++corner) {
            int cxx = ix0 + (corner & 1);
            int cyy = iy0 + (corner >> 1);
            bool vld = ((unsigned)cxx < 64u) && ((unsigned)cyy < 64u);
            float w = vld ? wts[corner] : 0.f;
            int cxc = min(max(cxx, 0), 63);
            int cyc = min(max(cyy, 0), 63);
            F4H kv;
            kv.f = *(const float4*)&kvp[(size_t)(cyc * 64 + cxc) * 64];
            __half2 w2 = __float2half2_rn(w);
            acc0 = __hfma2(kv.h[0], w2, acc0);
            acc1 = __hfma2(kv.h[1], w2, acc1);
            acc2 = __hfma2(kv.h[2], w2, acc2);
            acc3 = __hfma2(kv.h[3], w2, acc3);
        }
        av[n][0] = acc0; av[n][1] = acc1; av[n][2] = acc2; av[n][3] = acc3;
        float4 r0 = rb4[n * 4], r1 = rb4[n * 4 + 1];
        float2 a0 = __half22float2(acc0), a1 = __half22float2(acc1);
        float2 a2 = __half22float2(acc2), a3 = __half22float2(acc3);
        float part = qv[0] * (a0.x + r0.x) + qv[1] * (a0.y + r0.y)
                   + qv[2] * (a1.x + r0.z) + qv[3] * (a1.y + r0.w)
                   + qv[4] * (a2.x + r1.x) + qv[5] * (a2.y + r1.y)
                   + qv[6] * (a3.x + r1.z) + qv[7] * (a3.y + r1.w);
        part += __shfl_xor(part, 8, 64);    // combine j-slices (k-dot complete on k-lanes)
        part += __shfl_xor(part, 16, 64);   // broadcast k-dot to v-lanes
        logit[n] = part;
    }

    // ---- Phase 2: flat softmax over 9 ----
    float m = logit[0];
    #pragma unroll
    for (int n = 1; n < NTAP; ++n) m = fmaxf(m, logit[n]);
    float l = 0.f;
    #pragma unroll
    for (int n = 0; n < NTAP; ++n) { logit[n] = __expf(logit[n] - m); l += logit[n]; }
    const float inv = 1.f / l;

    // ---- Phase 3: weighted V sum (packed fp16 accumulate) ----
    __half2 o0 = __float2half2_rn(0.f), o1 = o0, o2 = o0, o3 = o0;
    #pragma unroll
    for (int n = 0; n < NTAP; ++n) {
        __half2 p2 = __float2half2_rn(logit[n]);
        o0 = __hfma2(av[n][0], p2, o0);
        o1 = __hfma2(av[n][1], p2, o1);
        o2 = __hfma2(av[n][2], p2, o2);
        o3 = __hfma2(av[n][3], p2, o3);
    }
    if (half) {   // v-lanes write
        float* ao = ws + OFF_AOT;
        const int cb = head * 16 + j * 8;
        float2 f0 = __half22float2(o0), f1 = __half22float2(o1);
        float2 f2 = __half22float2(o2), f3 = __half22float2(o3);
        ao[(size_t)(cb + 0) * BHW + pix] = f0.x * inv;
        ao[(size_t)(cb + 1) * BHW + pix] = f0.y * inv;
        ao[(size_t)(cb + 2) * BHW + pix] = f1.x * inv;
        ao[(size_t)(cb + 3) * BHW + pix] = f1.y * inv;
        ao[(size_t)(cb + 4) * BHW + pix] = f2.x * inv;
        ao[(size_t)(cb + 5) * BHW + pix] = f2.y * inv;
        ao[(size_t)(cb + 6) * BHW + pix] = f3.x * inv;
        ao[(size_t)(cb + 7) * BHW + pix] = f3.y * inv;
    }
}

// ------ k5: proj(64->256)+bias+residual, then cls head (256->80) ----
__global__ __launch_bounds__(256) void k5_proj_cls(
    const float* __restrict__ x, const float* __restrict__ bproj,
    const float* __restrict__ bcls, const float* __restrict__ wsr, float* __restrict__ out)
{
    __shared__ float tmp[DIM * 64];
    const int t = threadIdx.x;
    const int b = blockIdx.x >> 6, row = blockIdx.x & 63;
    const int p = t & 63;
    const int chunk = __builtin_amdgcn_readfirstlane(t >> 6);
    const float* ao  = wsr + OFF_AOT;
    const float* wpT = wsr + OFF_WPT;
    const float* wcT = wsr + OFF_WCT;
    const int pixcol = row * 64 + p;
    const int cb = chunk * 64;

    float acc[64];
    #pragma unroll
    for (int j = 0; j < 64; ++j) acc[j] = 0.f;
    const size_t aob = (size_t)b * HW + pixcol;
    #pragma unroll 4
    for (int cr = 0; cr < 64; ++cr) {
        float av = ao[(size_t)cr * BHW + aob];
        const float* wrow = wpT + cr * 256 + cb;
        #pragma unroll
        for (int j = 0; j < 64; ++j)
            acc[j] += av * wrow[j];
    }
    #pragma unroll
    for (int j = 0; j < 64; ++j) {
        int c = cb + j;
        tmp[c * 64 + p] = acc[j] + bproj[c] + x[(size_t)(b * DIM + c) * HW + pixcol];
    }
    __syncthreads();

    float acc2[20];
    #pragma unroll
    for (int j = 0; j < 20; ++j) acc2[j] = bcls[chunk * 20 + j];
    #pragma unroll 4
    for (int c = 0; c < 256; ++c) {
        float tv = tmp[c * 64 + p];
        const float* wrow = wcT + c * 80 + chunk * 20;
        #pragma unroll
        for (int j = 0; j < 20; ++j)
            acc2[j] += tv * wrow[j];
    }
    #pragma unroll
    for (int j = 0; j < 20; ++j)
        out[(size_t)(b * NCLS + chunk * 20 + j) * HW + pixcol] = acc2[j];
}

extern "C" void kernel_launch(void* const* d_in, const int* in_sizes, int n_in,
                              void* d_out, int out_size, void* d_ws, size_t ws_size,
                              hipStream_t stream)
{
    const float* x     = (const float*)d_in[0];
    const float* off   = (const float*)d_in[1];
    const float* g1    = (const float*)d_in[2];
    const float* b1    = (const float*)d_in[3];
    const float* wqkv  = (const float*)d_in[4];
    const float* wdw   = (const float*)d_in[5];
    const float* g2    = (const float*)d_in[6];
    const float* b2    = (const float*)d_in[7];
    const float* woff  = (const float*)d_in[8];
    const float* boff  = (const float*)d_in[9];
    const float* rpb   = (const float*)d_in[10];
    const float* wproj = (const float*)d_in[11];
    const float* bproj = (const float*)d_in[12];
    const float* wcls  = (const float*)d_in[13];
    const float* bcls  = (const float*)d_in[14];
    float* ws  = (float*)d_ws;
    float* out = (float*)d_out;

    hipLaunchKernelGGL(k0a_transpose, dim3(256), dim3(256), 0, stream, wqkv, g1, wproj, wcls, ws);
    hipLaunchKernelGGL(k0b_ab,        dim3(1),   dim3(192), 0, stream, wqkv, g1, b1, woff, ws);
    hipLaunchKernelGGL(k0c_stats,     dim3(512), dim3(256), 0, stream, x, ws);
    hipLaunchKernelGGL(k1_gemm,       dim3(1024), dim3(256), 0, stream, x, ws);
    hipLaunchKernelGGL(k2_off_feat,   dim3(1024), dim3(256), 0, stream, wdw, g2, b2, ws);
    hipLaunchKernelGGL(k3_pred_off,   dim3(1024), dim3(256), 0, stream, boff, off, ws);
    hipLaunchKernelGGL(k4_attn,       dim3(2048), dim3(256), 0, stream, rpb, ws);
    hipLaunchKernelGGL(k5_proj_cls,   dim3(512), dim3(256), 0, stream, x, bproj, bcls, ws, out);
}

// Round 8
// 273.041 us; speedup vs baseline: 1.1590x; 1.0230x over previous
//
#include <hip/hip_runtime.h>
#include <hip/hip_fp16.h>
#include <math.h>

// Problem constants
#define BB   8
#define HW   4096
#define BHW  32768
#define DIM  256
#define CR   64
#define GC   32
#define NHD  4
#define HC   16
#define NTAP 9
#define NCLS 80

// workspace layout (float offsets)
#define OFF_TMPG 0u          // k5 intermediate [256][B*HW] fp32     8,388,608
                             //   (overlays QP/QT/KT region — dead after k4)
#define OFF_QP   0u          // q planar   [B][64][H][W] fp32       2,097,152
#define OFF_QT   2097152u    // q pix-major[B*HW][64] fp16          1,048,576 (floats of space)
#define OFF_KT   4194304u    // KV fp16 [BG][HW][2 sub][k16|v16]    2,097,152 (floats of space)
#define OFF_T    8388608u    // t planar   [BG][32][H][W]           2,097,152
// --- overlap region: inside OFF_T's span, used only BEFORE k2 writes T ---
#define OFF_WQT  8388608u    // wqkv^T * g1  [256][192]             49,152
#define OFF_AB   8437760u    // A[192], B[192]                      384
#define OFF_STAT 8438144u    // m[32768], rs[32768]                 65,536
// ------------------------------------------------------------------------
#define OFF_OFFB 10485760u   // off planar [BG][18][H][W]           1,179,648
#define OFF_AOT  11665408u   // attn out   [64][B*HW] planar fp32   2,097,152
#define OFF_WPT  13762560u   // wproj^T [64][256]                   16,384
#define OFF_WCT  13778944u   // wcls^T  [256][80]                   20,480
#define OFF_WFT  13799424u   // woff^T  [9][32][18]                 5,184

// ---------------- k0a: weight transposes ----------------
__global__ __launch_bounds__(256) void k0a_transpose(
    const float* __restrict__ wqkv, const float* __restrict__ g1,
    const float* __restrict__ wproj, const float* __restrict__ wcls,
    float* __restrict__ ws)
{
    const int c = blockIdx.x;   // 0..255
    const int t = threadIdx.x;
    if (t < 192) ws[OFF_WQT + c * 192 + t] = wqkv[t * 256 + c] * g1[c];
    if (c < 64)  ws[OFF_WPT + c * 256 + t] = wproj[t * 64 + c];
    if (t < 80)  ws[OFF_WCT + c * 80 + t]  = wcls[t * 256 + c];
}

// ---------------- k0b: A/B LN-fold vectors + woff transpose ----------------
__global__ __launch_bounds__(192) void k0b_ab(
    const float* __restrict__ wqkv, const float* __restrict__ g1,
    const float* __restrict__ b1, const float* __restrict__ woff,
    float* __restrict__ ws)
{
    const int t = threadIdx.x; // 0..191
    float a = 0.f, bb = 0.f;
    for (int c = 0; c < 256; ++c) {
        float w = wqkv[t * 256 + c];
        a += w * g1[c]; bb += w * b1[c];
    }
    ws[OFF_AB + t] = a;
    ws[OFF_AB + 192 + t] = bb;
    for (int pair = t; pair < 288; pair += 192) {
        int wo = pair >> 5, ic = pair & 31;
        for (int o = 0; o < 18; ++o)
            ws[OFF_WFT + (wo * 32 + ic) * 18 + o] = woff[(o * 32 + ic) * 9 + wo];
    }
}

// ---------------- k0c: per-pixel LN stats ----------------
__global__ __launch_bounds__(256) void k0c_stats(
    const float* __restrict__ x, float* __restrict__ ws)
{
    __shared__ float psum[256], psq[256];
    const int t = threadIdx.x;
    const int b = blockIdx.x >> 6, row = blockIdx.x & 63;
    const int p = t & 63, q4 = t >> 6;
    const int colbase = row * 64 + p;
    float s = 0.f, ss = 0.f;
    for (int i = 0; i < 64; ++i) {
        int c = q4 * 64 + i;
        float v = x[(size_t)(b * DIM + c) * HW + colbase];
        s += v; ss += v * v;
    }
    psum[t] = s; psq[t] = ss;
    __syncthreads();
    if (t < 64) {
        float S = psum[t] + psum[64 + t] + psum[128 + t] + psum[192 + t];
        float Q = psq[t] + psq[64 + t] + psq[128 + t] + psq[192 + t];
        float m = S * (1.f / 256.f);
        float v = Q * (1.f / 256.f) - m * m;
        float* stat = ws + OFF_STAT;
        int gp = b * HW + row * 64 + t;
        stat[gp] = m;
        stat[BHW + gp] = rsqrtf(v + 1e-5f);
    }
}

// ---------------- k1: QKV GEMM (LN folded; fp16 q/KV epilogue) ----------------
// grid 1024: mhalf=blk>>9 (96 outputs each), (b,row)=blk&511. block 256.
__global__ __launch_bounds__(256) void k1_gemm(
    const float* __restrict__ x, float* __restrict__ ws)
{
    __shared__ float smem[8192];     // 2x 16KB staging; reused as 64x97 transpose tile
    const int t = threadIdx.x;
    const int mhalf = blockIdx.x >> 9;
    const int rb = blockIdx.x & 511;
    const int b = rb >> 6, row = rb & 63;
    const int p = t & 63;
    const int og = __builtin_amdgcn_readfirstlane(t >> 6);
    const int obase = mhalf * 96 + og * 24;
    const float* wqT = ws + OFF_WQT;
    const float* AB  = ws + OFF_AB;
    const float* stat = ws + OFF_STAT;
    const size_t xbase = (size_t)b * DIM * HW + row * 64;

    float acc[24];
    #pragma unroll
    for (int j = 0; j < 24; ++j) acc[j] = 0.f;

    #pragma unroll
    for (int j = 0; j < 4; ++j) {
        int idx4 = t + j * 256;
        int c = idx4 >> 4, p4 = (idx4 & 15) << 2;
        float4 v = *(const float4*)&x[xbase + (size_t)c * HW + p4];
        *(float4*)&smem[c * 64 + p4] = v;
    }
    __syncthreads();

    for (int kt = 0; kt < 4; ++kt) {
        const int cur = kt & 1;
        float4 pf[4];
        if (kt < 3) {
            #pragma unroll
            for (int j = 0; j < 4; ++j) {
                int idx4 = t + j * 256;
                int c = idx4 >> 4, p4 = (idx4 & 15) << 2;
                pf[j] = *(const float4*)&x[xbase + (size_t)((kt + 1) * 64 + c) * HW + p4];
            }
        }
        const float* wb = wqT + (size_t)kt * 64 * 192 + obase;
        #pragma unroll 8
        for (int c = 0; c < 64; ++c) {
            float xv = smem[cur * 4096 + c * 64 + p];
            #pragma unroll
            for (int j = 0; j < 24; ++j)
                acc[j] += wb[c * 192 + j] * xv;
        }
        if (kt < 3) {
            #pragma unroll
            for (int j = 0; j < 4; ++j) {
                int idx4 = t + j * 256;
                int c = idx4 >> 4, p4 = (idx4 & 15) << 2;
                *(float4*)&smem[(cur ^ 1) * 4096 + c * 64 + p4] = pf[j];
            }
            __syncthreads();
        }
    }
    __syncthreads();

    const int colbase = row * 64 + p;
    const int gp = b * HW + colbase;
    const float m = stat[gp], rsv = stat[BHW + gp];
    #pragma unroll
    for (int j = 0; j < 24; ++j) {
        int o = obase + j;
        smem[p * 97 + og * 24 + j] = rsv * (acc[j] - m * AB[o]) + AB[192 + o];
    }
    __syncthreads();

    float*  qp  = ws + OFF_QP;
    __half* qth = (__half*)(ws + OFF_QT);
    __half* kvh = (__half*)(ws + OFF_KT);
    const int colrow = row * 64;
    if (mhalf == 0) {
        // q planar fp32 (k2 input)
        #pragma unroll
        for (int it = 0; it < 16; ++it) {
            int idx = it * 256 + t;
            int o = idx >> 6, px = idx & 63;
            qp[(size_t)(b * 64 + o) * HW + colrow + px] = smem[px * 97 + o];
        }
        // q pixel-major fp16 (k4 input)
        #pragma unroll
        for (int it = 0; it < 16; ++it) {
            int idx = it * 256 + t;
            int px = idx >> 6, o = idx & 63;
            qth[(size_t)(b * HW + colrow + px) * 64 + o] = __float2half(smem[px * 97 + o]);
        }
        // k of bg=2b (tile cols 64..95)
        #pragma unroll
        for (int it = 0; it < 8; ++it) {
            int idx = it * 256 + t;
            int px = idx >> 5, ch32 = idx & 31;
            int s = ch32 >> 4, ch = ch32 & 15;
            kvh[(size_t)((2 * b) * HW + colrow + px) * 64 + s * 32 + ch]
                = __float2half(smem[px * 97 + 64 + ch32]);
        }
    } else {
        // k of bg=2b+1 (cols 0..31)
        #pragma unroll
        for (int it = 0; it < 8; ++it) {
            int idx = it * 256 + t;
            int px = idx >> 5, ch32 = idx & 31;
            int s = ch32 >> 4, ch = ch32 & 15;
            kvh[(size_t)((2 * b + 1) * HW + colrow + px) * 64 + s * 32 + ch]
                = __float2half(smem[px * 97 + ch32]);
        }
        // v of bg=2b (cols 32..63)
        #pragma unroll
        for (int it = 0; it < 8; ++it) {
            int idx = it * 256 + t;
            int px = idx >> 5, ch32 = idx & 31;
            int s = ch32 >> 4, ch = ch32 & 15;
            kvh[(size_t)((2 * b) * HW + colrow + px) * 64 + s * 32 + 16 + ch]
                = __float2half(smem[px * 97 + 32 + ch32]);
        }
        // v of bg=2b+1 (cols 64..95)
        #pragma unroll
        for (int it = 0; it < 8; ++it) {
            int idx = it * 256 + t;
            int px = idx >> 5, ch32 = idx & 31;
            int s = ch32 >> 4, ch = ch32 & 15;
            kvh[(size_t)((2 * b + 1) * HW + colrow + px) * 64 + s * 32 + 16 + ch]
                = __float2half(smem[px * 97 + 64 + ch32]);
        }
    }
}

// ------- k2: depthwise 3x3 + LN(32) + GELU, channel-split across waves -------
__global__ __launch_bounds__(256) void k2_off_feat(
    const float* __restrict__ wdw, const float* __restrict__ g2, const float* __restrict__ b2,
    float* __restrict__ ws)
{
    __shared__ float rsum[4][64], rsq[4][64], smv[64], srv[64];
    const int t = threadIdx.x;
    const int bg = blockIdx.x >> 6, row = blockIdx.x & 63;
    const int p = t & 63;
    const int cq = __builtin_amdgcn_readfirstlane(t >> 6);
    const int b = bg >> 1, g = bg & 1;
    const float* qp = ws + OFF_QP;
    float vals[8];
    float s = 0.f, ss = 0.f;
    #pragma unroll
    for (int i = 0; i < 8; ++i) {
        int ch = cq * 8 + i;
        const float* plane = qp + (size_t)(b * 64 + g * 32 + ch) * HW;
        float a = 0.f;
        #pragma unroll
        for (int dy = 0; dy < 3; ++dy) {
            int y = row + dy - 1;
            if ((unsigned)y >= 64u) continue;
            #pragma unroll
            for (int dx = 0; dx < 3; ++dx) {
                int xx = p + dx - 1;
                bool vld = (unsigned)xx < 64u;
                float q = plane[y * 64 + (vld ? xx : 0)];
                a += (vld ? q : 0.f) * wdw[ch * 9 + dy * 3 + dx];
            }
        }
        vals[i] = a; s += a; ss += a * a;
    }
    rsum[cq][p] = s; rsq[cq][p] = ss;
    __syncthreads();
    if (t < 64) {
        float S = rsum[0][t] + rsum[1][t] + rsum[2][t] + rsum[3][t];
        float Q = rsq[0][t] + rsq[1][t] + rsq[2][t] + rsq[3][t];
        float m = S * (1.f / 32.f);
        float v = Q * (1.f / 32.f) - m * m;
        smv[t] = m; srv[t] = rsqrtf(v + 1e-5f);
    }
    __syncthreads();
    float m = smv[p], rv = srv[p];
    float* tb = ws + OFF_T;
    #pragma unroll
    for (int i = 0; i < 8; ++i) {
        int ch = cq * 8 + i;
        float u = (vals[i] - m) * rv * g2[ch] + b2[ch];
        float ge = 0.5f * u * (1.f + erff(u * 0.70710678118654752f));
        tb[(size_t)(bg * 32 + ch) * HW + row * 64 + p] = ge;
    }
}

// ------- k3: 3x3 conv 32->18 + tanh*5 + base offset, ic-split across waves -------
__global__ __launch_bounds__(256) void k3_pred_off(
    const float* __restrict__ boff, const float* __restrict__ off_in,
    float* __restrict__ ws)
{
    __shared__ float part[4 * 18 * 64];
    const int t = threadIdx.x;
    const int bg = blockIdx.x >> 6, row = blockIdx.x & 63;
    const int p = t & 63;
    const int icq = __builtin_amdgcn_readfirstlane(t >> 6);
    const int b = bg >> 1;
    const float* tb = ws + OFF_T;
    const float* wfT = ws + OFF_WFT;
    float acc[18];
    #pragma unroll
    for (int o = 0; o < 18; ++o) acc[o] = 0.f;
    #pragma unroll
    for (int dy = 0; dy < 3; ++dy) {
        int y = row + dy - 1;
        if ((unsigned)y >= 64u) continue;
        #pragma unroll
        for (int dx = 0; dx < 3; ++dx) {
            int xx = p + dx - 1;
            bool vld = (unsigned)xx < 64u;
            int xc = vld ? xx : 0;
            int wo = dy * 3 + dx;
            #pragma unroll
            for (int i = 0; i < 8; ++i) {
                int ic = icq * 8 + i;
                float tv = tb[(size_t)(bg * 32 + ic) * HW + y * 64 + xc];
                tv = vld ? tv : 0.f;
                const float* wrow = wfT + (wo * 32 + ic) * 18;
                #pragma unroll
                for (int o = 0; o < 18; ++o)
                    acc[o] += tv * wrow[o];
            }
        }
    }
    #pragma unroll
    for (int o = 0; o < 18; ++o) part[(icq * 18 + o) * 64 + p] = acc[o];
    __syncthreads();
    float* ob = ws + OFF_OFFB;
    #pragma unroll
    for (int r = 0; r < 5; ++r) {
        int idx = t + r * 256;
        if (idx < 1152) {
            int o = idx >> 6, p2 = idx & 63;
            float v = part[o * 64 + p2] + part[(18 + o) * 64 + p2]
                    + part[(36 + o) * 64 + p2] + part[(54 + o) * 64 + p2] + boff[o];
            v = tanhf(v) * 5.0f + off_in[(size_t)(b * 18 + o) * HW + row * 64 + p2];
            ob[(size_t)(bg * 18 + o) * HW + row * 64 + p2] = v;
        }
    }
}

// ---- k4: deformable gather + softmax attn, fp16 KV, one wave = one group ----
__global__ __launch_bounds__(256, 2) void k4_attn(
    const float* __restrict__ rpb, float* __restrict__ ws)
{
    __shared__ float rpb_l[NHD * NTAP * HC]; // 576 floats
    for (int i = threadIdx.x; i < NHD * NTAP * HC; i += 256) rpb_l[i] = rpb[i];
    __syncthreads();

    const int t = threadIdx.x;
    const int wave = __builtin_amdgcn_readfirstlane(t >> 6);
    const int g = wave & 1, pxh = wave >> 1;
    const int lane = t & 63;
    const int pxl = lane & 7;
    const int prt = lane >> 3;
    const int s    = prt >> 2;
    const int half = (prt >> 1) & 1;
    const int j    = prt & 1;
    const int b = blockIdx.x & 7;
    const int chunk = blockIdx.x >> 3;          // 0..255
    const int hw = chunk * 16 + pxh * 8 + pxl;
    const int pix = b * HW + hw;
    const int bg = b * 2 + g;
    const int head = g * 2 + s;

    const __half* qth = (const __half*)(ws + OFF_QT);
    const __half* kvh = (const __half*)(ws + OFF_KT);
    const float*  ob  = ws + OFF_OFFB;

    union F4H { float4 f; __half2 h[4]; };
    F4H qld;
    qld.f = *(const float4*)&qth[(size_t)pix * 64 + g * 32 + s * 16 + j * 8];
    const float qs = half ? 0.0f : 0.25f;
    float qv[8];
    #pragma unroll
    for (int i = 0; i < 4; ++i) {
        float2 q2 = __half22float2(qld.h[i]);
        qv[2 * i] = q2.x * qs; qv[2 * i + 1] = q2.y * qs;
    }

    const float4* rb4 = (const float4*)(rpb_l + head * (NTAP * HC) + j * 8);
    const __half* kvp = kvh + (size_t)(bg * HW) * 64 + prt * 8;

    __half2 av[NTAP][4];
    float logit[NTAP];

    #pragma unroll
    for (int n = 0; n < NTAP; ++n) {
        float r = ob[(size_t)(bg * 18 + 2 * n) * HW + hw];
        float c = ob[(size_t)(bg * 18 + 2 * n + 1) * HW + hw];
        float y0f = floorf(r), x0f = floorf(c);
        float fy = r - y0f, fx = c - x0f;
        int iy0 = (int)y0f, ix0 = (int)x0f;
        float wts[4] = { (1.f - fx) * (1.f - fy), fx * (1.f - fy),
                         (1.f - fx) * fy,         fx * fy };
        __half2 acc0 = __float2half2_rn(0.f), acc1 = acc0, acc2 = acc0, acc3 = acc0;
        #pragma unroll
        for (int corner = 0; corner < 4; ++corner) {
            int cxx = ix0 + (corner & 1);
            int cyy = iy0 + (corner >> 1);
            bool vld = ((unsigned)cxx < 64u) && ((unsigned)cyy < 64u);
            float w = vld ? wts[corner] : 0.f;
            int cxc = min(max(cxx, 0), 63);
            int cyc = min(max(cyy, 0), 63);
            F4H kv;
            kv.f = *(const float4*)&kvp[(size_t)(cyc * 64 + cxc) * 64];
            __half2 w2 = __float2half2_rn(w);
            acc0 = __hfma2(kv.h[0], w2, acc0);
            acc1 = __hfma2(kv.h[1], w2, acc1);
            acc2 = __hfma2(kv.h[2], w2, acc2);
            acc3 = __hfma2(kv.h[3], w2, acc3);
        }
        av[n][0] = acc0; av[n][1] = acc1; av[n][2] = acc2; av[n][3] = acc3;
        float4 r0 = rb4[n * 4], r1 = rb4[n * 4 + 1];
        float2 a0 = __half22float2(acc0), a1 = __half22float2(acc1);
        float2 a2 = __half22float2(acc2), a3 = __half22float2(acc3);
        float part = qv[0] * (a0.x + r0.x) + qv[1] * (a0.y + r0.y)
                   + qv[2] * (a1.x + r0.z) + qv[3] * (a1.y + r0.w)
                   + qv[4] * (a2.x + r1.x) + qv[5] * (a2.y + r1.y)
                   + qv[6] * (a3.x + r1.z) + qv[7] * (a3.y + r1.w);
        part += __shfl_xor(part, 8, 64);
        part += __shfl_xor(part, 16, 64);
        logit[n] = part;
    }

    float m = logit[0];
    #pragma unroll
    for (int n = 1; n < NTAP; ++n) m = fmaxf(m, logit[n]);
    float l = 0.f;
    #pragma unroll
    for (int n = 0; n < NTAP; ++n) { logit[n] = __expf(logit[n] - m); l += logit[n]; }
    const float inv = 1.f / l;

    __half2 o0 = __float2half2_rn(0.f), o1 = o0, o2 = o0, o3 = o0;
    #pragma unroll
    for (int n = 0; n < NTAP; ++n) {
        __half2 p2 = __float2half2_rn(logit[n]);
        o0 = __hfma2(av[n][0], p2, o0);
        o1 = __hfma2(av[n][1], p2, o1);
        o2 = __hfma2(av[n][2], p2, o2);
        o3 = __hfma2(av[n][3], p2, o3);
    }
    if (half) {   // v-lanes write
        float* ao = ws + OFF_AOT;
        const int cb = head * 16 + j * 8;
        float2 f0 = __half22float2(o0), f1 = __half22float2(o1);
        float2 f2 = __half22float2(o2), f3 = __half22float2(o3);
        ao[(size_t)(cb + 0) * BHW + pix] = f0.x * inv;
        ao[(size_t)(cb + 1) * BHW + pix] = f0.y * inv;
        ao[(size_t)(cb + 2) * BHW + pix] = f1.x * inv;
        ao[(size_t)(cb + 3) * BHW + pix] = f1.y * inv;
        ao[(size_t)(cb + 4) * BHW + pix] = f2.x * inv;
        ao[(size_t)(cb + 5) * BHW + pix] = f2.y * inv;
        ao[(size_t)(cb + 6) * BHW + pix] = f3.x * inv;
        ao[(size_t)(cb + 7) * BHW + pix] = f3.y * inv;
    }
}

// ------ k5a: proj(64->256) + bias + residual -> tmpG planar [256][B*HW] ------
// grid 1024: mhalf=blk>>9 (128 ch each), (b,row)=blk&511. No LDS.
__global__ __launch_bounds__(256) void k5a_proj(
    const float* __restrict__ x, const float* __restrict__ bproj,
    float* __restrict__ ws)
{
    const int t = threadIdx.x;
    const int mhalf = blockIdx.x >> 9;
    const int rb = blockIdx.x & 511;
    const int b = rb >> 6, row = rb & 63;
    const int p = t & 63;
    const int wv = __builtin_amdgcn_readfirstlane(t >> 6);
    const int cb = mhalf * 128 + wv * 32;
    const float* ao  = ws + OFF_AOT;
    const float* wpT = ws + OFF_WPT;
    float* tmpG = ws + OFF_TMPG;
    const int pixcol = row * 64 + p;
    const size_t aob = (size_t)b * HW + pixcol;

    float acc[32];
    #pragma unroll
    for (int j = 0; j < 32; ++j) acc[j] = 0.f;
    #pragma unroll 4
    for (int cr = 0; cr < 64; ++cr) {
        float av = ao[(size_t)cr * BHW + aob];
        const float* wrow = wpT + cr * 256 + cb;
        #pragma unroll
        for (int j = 0; j < 32; ++j)
            acc[j] += av * wrow[j];
    }
    #pragma unroll
    for (int j = 0; j < 32; ++j) {
        int c = cb + j;
        tmpG[(size_t)c * BHW + aob] = acc[j] + bproj[c] + x[(size_t)(b * DIM + c) * HW + pixcol];
    }
}

// ------ k5b: cls head (256->80) from tmpG ------
// grid 1024: ochalf=blk>>9 (40 outputs each), (b,row)=blk&511. No LDS.
__global__ __launch_bounds__(256) void k5b_cls(
    const float* __restrict__ bcls, const float* __restrict__ wsr, float* __restrict__ out)
{
    const int t = threadIdx.x;
    const int ochalf = blockIdx.x >> 9;
    const int rb = blockIdx.x & 511;
    const int b = rb >> 6, row = rb & 63;
    const int p = t & 63;
    const int wv = __builtin_amdgcn_readfirstlane(t >> 6);
    const int oc0 = ochalf * 40 + wv * 10;
    const float* tmpG = wsr + OFF_TMPG;
    const float* wcT  = wsr + OFF_WCT;
    const int pixcol = row * 64 + p;
    const size_t pixb = (size_t)b * HW + pixcol;

    float acc2[10];
    #pragma unroll
    for (int j = 0; j < 10; ++j) acc2[j] = bcls[oc0 + j];
    #pragma unroll 4
    for (int c = 0; c < 256; ++c) {
        float tv = tmpG[(size_t)c * BHW + pixb];
        const float* wrow = wcT + c * 80 + oc0;
        #pragma unroll
        for (int j = 0; j < 10; ++j)
            acc2[j] += tv * wrow[j];
    }
    #pragma unroll
    for (int j = 0; j < 10; ++j)
        out[(size_t)(b * NCLS + oc0 + j) * HW + pixcol] = acc2[j];
}

extern "C" void kernel_launch(void* const* d_in, const int* in_sizes, int n_in,
                              void* d_out, int out_size, void* d_ws, size_t ws_size,
                              hipStream_t stream)
{
    const float* x     = (const float*)d_in[0];
    const float* off   = (const float*)d_in[1];
    const float* g1    = (const float*)d_in[2];
    const float* b1    = (const float*)d_in[3];
    const float* wqkv  = (const float*)d_in[4];
    const float* wdw   = (const float*)d_in[5];
    const float* g2    = (const float*)d_in[6];
    const float* b2    = (const float*)d_in[7];
    const float* woff  = (const float*)d_in[8];
    const float* boff  = (const float*)d_in[9];
    const float* rpb   = (const float*)d_in[10];
    const float* wproj = (const float*)d_in[11];
    const float* bproj = (const float*)d_in[12];
    const float* wcls  = (const float*)d_in[13];
    const float* bcls  = (const float*)d_in[14];
    float* ws  = (float*)d_ws;
    float* out = (float*)d_out;

    hipLaunchKernelGGL(k0a_transpose, dim3(256), dim3(256), 0, stream, wqkv, g1, wproj, wcls, ws);
    hipLaunchKernelGGL(k0b_ab,        dim3(1),   dim3(192), 0, stream, wqkv, g1, b1, woff, ws);
    hipLaunchKernelGGL(k0c_stats,     dim3(512), dim3(256), 0, stream, x, ws);
    hipLaunchKernelGGL(k1_gemm,       dim3(1024), dim3(256), 0, stream, x, ws);
    hipLaunchKernelGGL(k2_off_feat,   dim3(1024), dim3(256), 0, stream, wdw, g2, b2, ws);
    hipLaunchKernelGGL(k3_pred_off,   dim3(1024), dim3(256), 0, stream, boff, off, ws);
    hipLaunchKernelGGL(k4_attn,       dim3(2048), dim3(256), 0, stream, rpb, ws);
    hipLaunchKernelGGL(k5a_proj,      dim3(1024), dim3(256), 0, stream, x, bproj, ws);
    hipLaunchKernelGGL(k5b_cls,       dim3(1024), dim3(256), 0, stream, bcls, ws, out);
}